// Round 11
// baseline (29.244 us; speedup 1.0000x reference)
//
#include <hip/hip_runtime.h>

// similarity[r] = sum_a (pp[r,a] - ph[a])^2, a in [0,32); output = min_r similarity[r]
// pp: [R, 32] fp32 row-major, ph: [32] fp32, out: 1 fp32 scalar.
//
// Round-11: r10's stage kept byte-identical (25.58 us, stage ~97% of the
// 6.29 TB/s achievable read BW). ONE change: the reducer shrinks from
// 1024 threads / 16 waves / LDS combine to a SINGLE wave:
//   - 16 fully-unrolled predicated float4 loads per lane (976 float4s, one
//     latency generation, no runtime-trip-count loop),
//   - 3-element scalar tail, 6-step shuffle butterfly, lane 0 stores.
//   - No LDS, no barriers, no serial per-wave chain in thread 0.

__global__ __launch_bounds__(256) void doa_stage_kernel(
    const float* __restrict__ pp,
    const float* __restrict__ ph,
    float* __restrict__ ws,
    int R)
{
    const int t = threadIdx.x;
    const long long base_row = (long long)blockIdx.x * 256;

    // this thread's fixed 4-float chunk of the phase vector (k = t&7)
    const float4 qk = reinterpret_cast<const float4*>(ph)[t & 7];

    // 8 independent coalesced float4 loads (1 KB per wave instruction)
    const float4* src = reinterpret_cast<const float4*>(pp);
    const long long gmax = (long long)R * 8;
    float4 v[8];
#pragma unroll
    for (int i = 0; i < 8; ++i) {
        long long g = base_row * 8 + i * 256 + t;
        if (g >= gmax) g = 0;          // clamp; value unused for r >= R
        v[i] = src[g];
    }

    float lmin = __builtin_inff();
#pragma unroll
    for (int i = 0; i < 8; ++i) {
        const float dx = v[i].x - qk.x;
        const float dy = v[i].y - qk.y;
        const float dz = v[i].z - qk.z;
        const float dw = v[i].w - qk.w;
        float s = dx * dx + dy * dy + dz * dz + dw * dw;
        // sum the 8 chunks of this row across the 8-lane group
        s += __shfl_xor(s, 1);
        s += __shfl_xor(s, 2);
        s += __shfl_xor(s, 4);
        const long long row = base_row + i * 32 + (t >> 3);
        if (row < R) lmin = fminf(lmin, s);
    }

    // lanes within each 8-group already share lmin; fold across groups
    lmin = fminf(lmin, __shfl_xor(lmin, 8));
    lmin = fminf(lmin, __shfl_xor(lmin, 16));
    lmin = fminf(lmin, __shfl_xor(lmin, 32));

    __shared__ float wmin[4];
    if ((t & 63) == 0) wmin[t >> 6] = lmin;
    __syncthreads();
    if (t == 0) {
        // plain store: fire-and-forget, no atomic tail
        ws[blockIdx.x] = fminf(fminf(wmin[0], wmin[1]), fminf(wmin[2], wmin[3]));
    }
}

__global__ __launch_bounds__(64) void doa_reduce_kernel(
    const float* __restrict__ ws,
    float* __restrict__ out,
    int n)
{
    const int t = threadIdx.x;            // single wave
    const int n4 = n >> 2;                // 976 float4 for n = 3907

    float s = __builtin_inff();
    const float4* w4 = reinterpret_cast<const float4*>(ws);
    // 16 independent predicated loads: one latency generation, full MLP
#pragma unroll
    for (int j = 0; j < 16; ++j) {
        const int i = t + j * 64;
        if (i < n4) {
            const float4 p = w4[i];
            s = fminf(fminf(s, fminf(p.x, p.y)), fminf(p.z, p.w));
        }
    }
    // scalar tail (n & 3 elements)
    if (t < (n & 3)) s = fminf(s, ws[(n4 << 2) + t]);

    // wave butterfly; all lanes converge, lane 0 stores
#pragma unroll
    for (int off = 1; off < 64; off <<= 1)
        s = fminf(s, __shfl_xor(s, off));

    if (t == 0) *out = s;
}

extern "C" void kernel_launch(void* const* d_in, const int* in_sizes, int n_in,
                              void* d_out, int out_size, void* d_ws, size_t ws_size,
                              hipStream_t stream) {
    const float* pp = (const float*)d_in[0];   // possible_phases [R, 32]
    const float* ph = (const float*)d_in[1];   // phases [32]
    float* out = (float*)d_out;                // 1 fp32 scalar
    float* ws  = (float*)d_ws;                 // per-block partial mins

    const int R = in_sizes[0] / 32;
    const int grid = (R + 255) / 256;          // 3907 blocks for R = 1e6

    doa_stage_kernel<<<grid, 256, 0, stream>>>(pp, ph, ws, R);
    doa_reduce_kernel<<<1, 64, 0, stream>>>(ws, out, grid);
}

// Round 12
// 25.620 us; speedup vs baseline: 1.1415x; 1.1415x over previous
//
#include <hip/hip_runtime.h>

// similarity[r] = sum_a (pp[r,a] - ph[a])^2, a in [0,32); output = min_r similarity[r]
// pp: [R, 32] fp32 row-major, ph: [32] fp32, out: 1 fp32 scalar.
//
// Round-12: byte-identical revert to round 10 — the empirical optimum
// (25.58 us; stage at ~97% of the 6.29 TB/s achievable read BW).
//
// Structure: two-node graph.
//  Stage: key identity — with coalesced float4 index g = blk*2048 + i*256 + t,
//  chunk id (g & 7) == (t & 7) for ALL i. Each thread's 8 coalesced loads are
//  the SAME k-chunk of 8 different rows:
//   - 8 independent float4 loads (full MLP, 1 KB/wave-instr),
//   - per row: 4-elem squared diff vs the thread's fixed q-chunk + 3-step
//     __shfl_xor sum across the 8-lane group; running min.
//   - No LDS tile, no barriers -> 8 blocks/CU; no spill.
//  Partials: plain store per block (fire-and-forget; atomics cost +1..+112 us
//  in rounds 5-7). Reducer: 1024 threads, one float4 load generation (TLP
//  hides cross-XCD latency; 1-wave version cost +3.7 us in round 11).

__global__ __launch_bounds__(256) void doa_stage_kernel(
    const float* __restrict__ pp,
    const float* __restrict__ ph,
    float* __restrict__ ws,
    int R)
{
    const int t = threadIdx.x;
    const long long base_row = (long long)blockIdx.x * 256;

    // this thread's fixed 4-float chunk of the phase vector (k = t&7)
    const float4 qk = reinterpret_cast<const float4*>(ph)[t & 7];

    // 8 independent coalesced float4 loads (identical addressing to r4)
    const float4* src = reinterpret_cast<const float4*>(pp);
    const long long gmax = (long long)R * 8;
    float4 v[8];
#pragma unroll
    for (int i = 0; i < 8; ++i) {
        long long g = base_row * 8 + i * 256 + t;
        if (g >= gmax) g = 0;          // clamp; value unused for r >= R
        v[i] = src[g];
    }

    float lmin = __builtin_inff();
#pragma unroll
    for (int i = 0; i < 8; ++i) {
        const float dx = v[i].x - qk.x;
        const float dy = v[i].y - qk.y;
        const float dz = v[i].z - qk.z;
        const float dw = v[i].w - qk.w;
        float s = dx * dx + dy * dy + dz * dz + dw * dw;
        // sum the 8 chunks of this row across the 8-lane group
        s += __shfl_xor(s, 1);
        s += __shfl_xor(s, 2);
        s += __shfl_xor(s, 4);
        const long long row = base_row + i * 32 + (t >> 3);
        if (row < R) lmin = fminf(lmin, s);
    }

    // lanes within each 8-group already share lmin; fold across groups
    lmin = fminf(lmin, __shfl_xor(lmin, 8));
    lmin = fminf(lmin, __shfl_xor(lmin, 16));
    lmin = fminf(lmin, __shfl_xor(lmin, 32));

    __shared__ float wmin[4];
    if ((t & 63) == 0) wmin[t >> 6] = lmin;
    __syncthreads();
    if (t == 0) {
        // plain store: fire-and-forget, no atomic tail
        ws[blockIdx.x] = fminf(fminf(wmin[0], wmin[1]), fminf(wmin[2], wmin[3]));
    }
}

__global__ __launch_bounds__(1024) void doa_reduce_kernel(
    const float* __restrict__ ws,
    float* __restrict__ out,
    int n)
{
    const int t = threadIdx.x;
    const int n4 = n >> 2;             // float4 count (976 for n=3907)

    float s = __builtin_inff();
    // one float4 load generation covers all partials (n4 <= 1024)
    for (int i = t; i < n4; i += 1024) {
        const float4 p = reinterpret_cast<const float4*>(ws)[i];
        s = fminf(fminf(s, fminf(p.x, p.y)), fminf(p.z, p.w));
    }
    // scalar tail (n & 3 elements)
    if (t < (n & 3)) s = fminf(s, ws[(n4 << 2) + t]);

#pragma unroll
    for (int off = 1; off < 64; off <<= 1)
        s = fminf(s, __shfl_xor(s, off));

    __shared__ float wmin[16];
    if ((t & 63) == 0) wmin[t >> 6] = s;
    __syncthreads();
    if (t == 0) {
        float m = wmin[0];
#pragma unroll
        for (int w = 1; w < 16; ++w) m = fminf(m, wmin[w]);
        *out = m;
    }
}

extern "C" void kernel_launch(void* const* d_in, const int* in_sizes, int n_in,
                              void* d_out, int out_size, void* d_ws, size_t ws_size,
                              hipStream_t stream) {
    const float* pp = (const float*)d_in[0];   // possible_phases [R, 32]
    const float* ph = (const float*)d_in[1];   // phases [32]
    float* out = (float*)d_out;                // 1 fp32 scalar
    float* ws  = (float*)d_ws;                 // per-block partial mins

    const int R = in_sizes[0] / 32;
    const int grid = (R + 255) / 256;          // 3907 blocks for R = 1e6

    doa_stage_kernel<<<grid, 256, 0, stream>>>(pp, ph, ws, R);
    doa_reduce_kernel<<<1, 1024, 0, stream>>>(ws, out, grid);
}